// Round 1
// baseline (193.575 us; speedup 1.0000x reference)
//
#include <hip/hip_runtime.h>
#include <hip/hip_bf16.h>

// Problem constants (fixed by setup_inputs)
#define BATCH 4
#define NNODES 4096
#define HID 256
#define NHEADS 8
#define DH 32
#define DEG 16
#define NEDGES (BATCH * NNODES * DEG)   // 262144
#define NROWS (BATCH * NNODES)          // 16384 node-rows

// ---------------------------------------------------------------------------
// Kernel 1: fused Q/K/V projection.  C = X @ W + b for three weight matrices.
// Grid: NROWS/16 blocks, 256 threads. Each block stages 16 X-rows in LDS,
// thread t computes output column t for all 16 rows (register tile acc[16]).
// LDS reads are wave-uniform (broadcast) ds_read_b128; W loads are coalesced.
// ---------------------------------------------------------------------------
__global__ __launch_bounds__(256) void qkv_proj_kernel(
    const float* __restrict__ X,
    const float* __restrict__ Wq, const float* __restrict__ bq,
    const float* __restrict__ Wk, const float* __restrict__ bk,
    const float* __restrict__ Wv, const float* __restrict__ bv,
    float* __restrict__ Qo, float* __restrict__ Ko, float* __restrict__ Vo) {
  __shared__ float xs[16][HID];
  const int row0 = blockIdx.x * 16;
  const int t = threadIdx.x;

  #pragma unroll
  for (int r = 0; r < 16; ++r) {
    xs[r][t] = X[(size_t)(row0 + r) * HID + t];
  }
  __syncthreads();

  const float* Ws[3] = {Wq, Wk, Wv};
  const float* bs[3] = {bq, bk, bv};
  float* Os[3] = {Qo, Ko, Vo};

  #pragma unroll
  for (int m = 0; m < 3; ++m) {
    const float* __restrict__ W = Ws[m];
    float* __restrict__ O = Os[m];
    const float bias = bs[m][t];
    float acc[16];
    #pragma unroll
    for (int r = 0; r < 16; ++r) acc[r] = bias;

    for (int k = 0; k < HID; k += 4) {
      const float w0 = W[(size_t)(k + 0) * HID + t];
      const float w1 = W[(size_t)(k + 1) * HID + t];
      const float w2 = W[(size_t)(k + 2) * HID + t];
      const float w3 = W[(size_t)(k + 3) * HID + t];
      #pragma unroll
      for (int r = 0; r < 16; ++r) {
        const float4 x4 = *reinterpret_cast<const float4*>(&xs[r][k]);
        float a = acc[r];
        a = fmaf(x4.x, w0, a);
        a = fmaf(x4.y, w1, a);
        a = fmaf(x4.z, w2, a);
        a = fmaf(x4.w, w3, a);
        acc[r] = a;
      }
    }

    #pragma unroll
    for (int r = 0; r < 16; ++r) {
      O[(size_t)(row0 + r) * HID + t] = acc[r];
    }
    __syncthreads();  // keep xs live/ordered across the (unrolled) m-loop
  }
}

// ---------------------------------------------------------------------------
// Kernel 2: per-segment attention. One block per (b, target) segment of 16
// consecutive edges. 256 threads = 8 heads x 32 dh; tid == hidden channel.
// Scores: q*k partial per lane, reduced over dh=32 lanes via shfl_xor
// (masks 1..16 stay inside each 32-lane half-wave = one head group).
// ---------------------------------------------------------------------------
__global__ __launch_bounds__(256) void attn_kernel(
    const float* __restrict__ Q, const float* __restrict__ K,
    const float* __restrict__ V, const int* __restrict__ edges,
    float* __restrict__ out) {
  __shared__ int s_src[DEG];
  __shared__ int s_bt[2];

  const int g = blockIdx.x;       // segment id = b*N + t (by construction)
  const int tid = threadIdx.x;    // channel index 0..255
  const int e0 = g * DEG;

  if (tid < DEG) s_src[tid] = edges[2 * NEDGES + e0 + tid];  // src row
  if (tid == DEG)     s_bt[0] = edges[e0];                   // batch row
  if (tid == DEG + 1) s_bt[1] = edges[NEDGES + e0];          // target row
  __syncthreads();

  const int b = s_bt[0];
  const int tgt = s_bt[1];
  const int qrow = b * NNODES + tgt;

  const float q = Q[(size_t)qrow * HID + tid];

  float sc[DEG];
  #pragma unroll
  for (int j = 0; j < DEG; ++j) {
    const int n = b * NNODES + s_src[j];
    const float kv = K[(size_t)n * HID + tid];
    float p = q * kv;
    p += __shfl_xor(p, 1);
    p += __shfl_xor(p, 2);
    p += __shfl_xor(p, 4);
    p += __shfl_xor(p, 8);
    p += __shfl_xor(p, 16);
    sc[j] = p * 0.17677669529663687f;  // 1/sqrt(DH)
  }

  float m = sc[0];
  #pragma unroll
  for (int j = 1; j < DEG; ++j) m = fmaxf(m, sc[j]);

  float sum = 0.0f;
  #pragma unroll
  for (int j = 0; j < DEG; ++j) {
    sc[j] = __expf(sc[j] - m);
    sum += sc[j];
  }
  const float inv = 1.0f / sum;

  float acc = 0.0f;
  #pragma unroll
  for (int j = 0; j < DEG; ++j) {
    const int n = b * NNODES + s_src[j];
    acc = fmaf(sc[j], V[(size_t)n * HID + tid], acc);
  }

  out[(size_t)qrow * HID + tid] = acc * inv;
}

// ---------------------------------------------------------------------------
extern "C" void kernel_launch(void* const* d_in, const int* in_sizes, int n_in,
                              void* d_out, int out_size, void* d_ws, size_t ws_size,
                              hipStream_t stream) {
  const float* X     = (const float*)d_in[0];   // (B, N, H) fp32
  const int*   edges = (const int*)d_in[1];     // (3, E) int32
  const float* Wq    = (const float*)d_in[2];
  const float* bq    = (const float*)d_in[3];
  const float* Wk    = (const float*)d_in[4];
  const float* bk    = (const float*)d_in[5];
  const float* Wv    = (const float*)d_in[6];
  const float* bv    = (const float*)d_in[7];
  float* out = (float*)d_out;

  // Workspace: Q, K, V each NROWS*HID fp32 = 16 MiB -> 48 MiB total.
  float* Qs = (float*)d_ws;
  float* Ks = Qs + (size_t)NROWS * HID;
  float* Vs = Ks + (size_t)NROWS * HID;

  qkv_proj_kernel<<<NROWS / 16, 256, 0, stream>>>(X, Wq, bq, Wk, bk, Wv, bv,
                                                  Qs, Ks, Vs);
  attn_kernel<<<NROWS, 256, 0, stream>>>(Qs, Ks, Vs, edges, out);
}

// Round 2
// 102.983 us; speedup vs baseline: 1.8797x; 1.8797x over previous
//
#include <hip/hip_runtime.h>
#include <hip/hip_bf16.h>

// Problem constants (fixed by setup_inputs)
#define BATCH 4
#define NNODES 4096
#define HID 256
#define NHEADS 8
#define DH 32
#define DEG 16
#define NEDGES (BATCH * NNODES * DEG)   // 262144
#define NROWS (BATCH * NNODES)          // 16384 node-rows

typedef __attribute__((ext_vector_type(8))) short short8;
typedef __attribute__((ext_vector_type(8))) unsigned short ushort8;
typedef __attribute__((ext_vector_type(4))) float f32x4;

static __device__ __forceinline__ unsigned short f2bf(float f) {
  __hip_bfloat16 h = __float2bfloat16(f);  // RNE
  return *reinterpret_cast<unsigned short*>(&h);
}
static __device__ __forceinline__ float bf2f(unsigned short u) {
  unsigned int v = ((unsigned int)u) << 16;
  return *reinterpret_cast<float*>(&v);
}

// ---------------------------------------------------------------------------
// Prep: convert X to bf16 (blocks [0,2048)), build Wt[m][n][k] = bf16(W_m[k][n])
// (blocks [2048, 2048+96)). Each thread handles 8 consecutive outputs.
// ---------------------------------------------------------------------------
#define XBLOCKS 2048
#define WBLOCKS 96
__global__ __launch_bounds__(256) void prep_kernel(
    const float* __restrict__ X,
    const float* __restrict__ Wq, const float* __restrict__ Wk,
    const float* __restrict__ Wv,
    unsigned short* __restrict__ Xb, unsigned short* __restrict__ Wt) {
  const int tid = threadIdx.x;
  if (blockIdx.x < XBLOCKS) {
    const size_t base = (size_t)blockIdx.x * 2048 + (size_t)tid * 8;
    const float4 a = *reinterpret_cast<const float4*>(&X[base]);
    const float4 b = *reinterpret_cast<const float4*>(&X[base + 4]);
    ushort8 o;
    o[0] = f2bf(a.x); o[1] = f2bf(a.y); o[2] = f2bf(a.z); o[3] = f2bf(a.w);
    o[4] = f2bf(b.x); o[5] = f2bf(b.y); o[6] = f2bf(b.z); o[7] = f2bf(b.w);
    *reinterpret_cast<ushort8*>(&Xb[base]) = o;
  } else {
    // Wt output index o = m*65536 + n*256 + k, 8 consecutive k per thread.
    const int o = (blockIdx.x - XBLOCKS) * 2048 + tid * 8;
    const int m = o >> 16;
    const int rem = o & 65535;
    const int n = rem >> 8;
    const int k0 = rem & 255;
    const float* __restrict__ W = (m == 0) ? Wq : (m == 1) ? Wk : Wv;
    ushort8 ovec;
    #pragma unroll
    for (int j = 0; j < 8; ++j) {
      ovec[j] = f2bf(W[(size_t)(k0 + j) * HID + n]);
    }
    *reinterpret_cast<ushort8*>(&Wt[o]) = ovec;
  }
}

// ---------------------------------------------------------------------------
// MFMA projection. 384 blocks x 256 threads = 1536 waves.
// Wave gw: strip s = gw%12 (mat = s>>2, cols [ (s&3)*64, +64 )),
// row chunk = gw/12 (8 row-tiles of 16 rows each).
// B-frags (W^T, [n][k] per lane: col = c0+n*16+(lane&15), k = k*32+(lane>>4)*8)
// held in registers for the whole wave; A-frags loaded per row-tile from Xb.
// Verified m92 fragment pattern: A row-major [m][k], B^T row-major [n][k],
// 8 consecutive k per lane; D: col=lane&15, row=(lane>>4)*4+reg.
// ---------------------------------------------------------------------------
__global__ __launch_bounds__(256) void qkv_mfma_kernel(
    const unsigned short* __restrict__ Xb, const unsigned short* __restrict__ Wt,
    const float* __restrict__ bq, const float* __restrict__ bk,
    const float* __restrict__ bv,
    float* __restrict__ Qs, unsigned short* __restrict__ Kb,
    unsigned short* __restrict__ Vb) {
  const int lane = threadIdx.x & 63;
  const int gw = blockIdx.x * 4 + (threadIdx.x >> 6);
  const int s = gw % 12;
  const int chunk = gw / 12;      // 0..127
  const int mat = s >> 2;         // 0=Q 1=K 2=V
  const int c0 = (s & 3) * 64;
  const unsigned short* __restrict__ W = Wt + (size_t)mat * 65536;

  const int lm = lane & 15;
  const int lk = (lane >> 4) * 8;

  short8 Bf[4][8];
  #pragma unroll
  for (int n = 0; n < 4; ++n) {
    #pragma unroll
    for (int k = 0; k < 8; ++k) {
      Bf[n][k] = *reinterpret_cast<const short8*>(
          &W[(size_t)(c0 + n * 16 + lm) * 256 + k * 32 + lk]);
    }
  }

  const float* __restrict__ bias = (mat == 0) ? bq : (mat == 1) ? bk : bv;
  float bias4[4];
  #pragma unroll
  for (int n = 0; n < 4; ++n) bias4[n] = bias[c0 + n * 16 + lm];

  for (int i = 0; i < 8; ++i) {
    const int r0 = (chunk * 8 + i) * 16;
    short8 Af[8];
    #pragma unroll
    for (int k = 0; k < 8; ++k) {
      Af[k] = *reinterpret_cast<const short8*>(
          &Xb[(size_t)(r0 + lm) * 256 + k * 32 + lk]);
    }
    f32x4 acc[4] = {f32x4{0,0,0,0}, f32x4{0,0,0,0}, f32x4{0,0,0,0}, f32x4{0,0,0,0}};
    #pragma unroll
    for (int n = 0; n < 4; ++n) {
      #pragma unroll
      for (int k = 0; k < 8; ++k) {
        acc[n] = __builtin_amdgcn_mfma_f32_16x16x32_bf16(Af[k], Bf[n][k], acc[n], 0, 0, 0);
      }
    }
    #pragma unroll
    for (int n = 0; n < 4; ++n) {
      const int col = c0 + n * 16 + lm;
      #pragma unroll
      for (int r = 0; r < 4; ++r) {
        const int row = r0 + (lane >> 4) * 4 + r;
        const float vres = acc[n][r] + bias4[n];
        if (mat == 0)      Qs[(size_t)row * 256 + col] = vres;
        else if (mat == 1) Kb[(size_t)row * 256 + col] = f2bf(vres);
        else               Vb[(size_t)row * 256 + col] = f2bf(vres);
      }
    }
  }
}

// ---------------------------------------------------------------------------
// Attention: one block per segment of 16 consecutive edges; 256 threads =
// 8 heads x 32 dh channels. Q fp32, K/V bf16 (halved gather traffic).
// ---------------------------------------------------------------------------
__global__ __launch_bounds__(256) void attn_kernel(
    const float* __restrict__ Q, const unsigned short* __restrict__ K,
    const unsigned short* __restrict__ V, const int* __restrict__ edges,
    float* __restrict__ out) {
  __shared__ int s_src[DEG];
  __shared__ int s_bt[2];

  const int g = blockIdx.x;
  const int tid = threadIdx.x;
  const int e0 = g * DEG;

  if (tid < DEG) s_src[tid] = edges[2 * NEDGES + e0 + tid];
  if (tid == DEG)     s_bt[0] = edges[e0];
  if (tid == DEG + 1) s_bt[1] = edges[NEDGES + e0];
  __syncthreads();

  const int b = s_bt[0];
  const int tgt = s_bt[1];
  const int qrow = b * NNODES + tgt;

  const float q = Q[(size_t)qrow * HID + tid];

  float sc[DEG];
  #pragma unroll
  for (int j = 0; j < DEG; ++j) {
    const int n = b * NNODES + s_src[j];
    const float kv = bf2f(K[(size_t)n * HID + tid]);
    float p = q * kv;
    p += __shfl_xor(p, 1);
    p += __shfl_xor(p, 2);
    p += __shfl_xor(p, 4);
    p += __shfl_xor(p, 8);
    p += __shfl_xor(p, 16);
    sc[j] = p * 0.17677669529663687f;  // 1/sqrt(DH)
  }

  float m = sc[0];
  #pragma unroll
  for (int j = 1; j < DEG; ++j) m = fmaxf(m, sc[j]);

  float sum = 0.0f;
  #pragma unroll
  for (int j = 0; j < DEG; ++j) {
    sc[j] = __expf(sc[j] - m);
    sum += sc[j];
  }
  const float inv = 1.0f / sum;

  float acc = 0.0f;
  #pragma unroll
  for (int j = 0; j < DEG; ++j) {
    const int n = b * NNODES + s_src[j];
    acc = fmaf(sc[j], bf2f(V[(size_t)n * HID + tid]), acc);
  }

  out[(size_t)qrow * HID + tid] = acc * inv;
}

// ---------------------------------------------------------------------------
extern "C" void kernel_launch(void* const* d_in, const int* in_sizes, int n_in,
                              void* d_out, int out_size, void* d_ws, size_t ws_size,
                              hipStream_t stream) {
  const float* X     = (const float*)d_in[0];
  const int*   edges = (const int*)d_in[1];
  const float* Wq    = (const float*)d_in[2];
  const float* bq    = (const float*)d_in[3];
  const float* Wk    = (const float*)d_in[4];
  const float* bk    = (const float*)d_in[5];
  const float* Wv    = (const float*)d_in[6];
  const float* bv    = (const float*)d_in[7];
  float* out = (float*)d_out;

  // Workspace layout (bytes):
  //   Qs   fp32  NROWS*HID*4 = 16 MiB
  //   Kb   bf16  NROWS*HID*2 =  8 MiB
  //   Vb   bf16  NROWS*HID*2 =  8 MiB
  //   Xb   bf16  NROWS*HID*2 =  8 MiB
  //   Wt   bf16  3*HID*HID*2 = 384 KiB        total ~40.4 MiB
  char* w = (char*)d_ws;
  float*          Qs = (float*)w;                 w += (size_t)NROWS * HID * 4;
  unsigned short* Kb = (unsigned short*)w;        w += (size_t)NROWS * HID * 2;
  unsigned short* Vb = (unsigned short*)w;        w += (size_t)NROWS * HID * 2;
  unsigned short* Xb = (unsigned short*)w;        w += (size_t)NROWS * HID * 2;
  unsigned short* Wt = (unsigned short*)w;

  prep_kernel<<<XBLOCKS + WBLOCKS, 256, 0, stream>>>(X, Wq, Wk, Wv, Xb, Wt);
  qkv_mfma_kernel<<<384, 256, 0, stream>>>(Xb, Wt, bq, bk, bv, Qs, Kb, Vb);
  attn_kernel<<<NROWS, 256, 0, stream>>>(Qs, Kb, Vb, edges, out);
}

// Round 3
// 86.394 us; speedup vs baseline: 2.2406x; 1.1920x over previous
//
#include <hip/hip_runtime.h>
#include <hip/hip_bf16.h>

// Problem constants (fixed by setup_inputs)
#define BATCH 4
#define NNODES 4096
#define HID 256
#define NHEADS 8
#define DH 32
#define DEG 16
#define NEDGES (BATCH * NNODES * DEG)   // 262144
#define NROWS (BATCH * NNODES)          // 16384 node-rows

typedef __attribute__((ext_vector_type(8))) short short8;
typedef __attribute__((ext_vector_type(8))) unsigned short ushort8;
typedef __attribute__((ext_vector_type(4))) float f32x4;

static __device__ __forceinline__ unsigned short f2bf(float f) {
  __hip_bfloat16 h = __float2bfloat16(f);  // RNE
  return *reinterpret_cast<unsigned short*>(&h);
}
static __device__ __forceinline__ float bf2f(unsigned short u) {
  unsigned int v = ((unsigned int)u) << 16;
  return *reinterpret_cast<float*>(&v);
}

// ---------------------------------------------------------------------------
// Prep: X -> bf16 (blocks [0,2048)); Wt[m][n][k] = bf16(W_m[k][n]) (96 blocks).
// ---------------------------------------------------------------------------
#define XBLOCKS 2048
#define WBLOCKS 96
__global__ __launch_bounds__(256) void prep_kernel(
    const float* __restrict__ X,
    const float* __restrict__ Wq, const float* __restrict__ Wk,
    const float* __restrict__ Wv,
    unsigned short* __restrict__ Xb, unsigned short* __restrict__ Wt) {
  const int tid = threadIdx.x;
  if (blockIdx.x < XBLOCKS) {
    const size_t base = (size_t)blockIdx.x * 2048 + (size_t)tid * 8;
    const float4 a = *reinterpret_cast<const float4*>(&X[base]);
    const float4 b = *reinterpret_cast<const float4*>(&X[base + 4]);
    ushort8 o;
    o[0] = f2bf(a.x); o[1] = f2bf(a.y); o[2] = f2bf(a.z); o[3] = f2bf(a.w);
    o[4] = f2bf(b.x); o[5] = f2bf(b.y); o[6] = f2bf(b.z); o[7] = f2bf(b.w);
    *reinterpret_cast<ushort8*>(&Xb[base]) = o;
  } else {
    const int o = (blockIdx.x - XBLOCKS) * 2048 + tid * 8;
    const int m = o >> 16;
    const int rem = o & 65535;
    const int n = rem >> 8;
    const int k0 = rem & 255;
    const float* __restrict__ W = (m == 0) ? Wq : (m == 1) ? Wk : Wv;
    ushort8 ovec;
    #pragma unroll
    for (int j = 0; j < 8; ++j) {
      ovec[j] = f2bf(W[(size_t)(k0 + j) * HID + n]);
    }
    *reinterpret_cast<ushort8*>(&Wt[o]) = ovec;
  }
}

// ---------------------------------------------------------------------------
// MFMA projection. 3072 blocks x 4 waves = 12288 waves.
// Wave gw: strip s = gw%24 (mat = s>>3, cols [(s&7)*32, +32)),
// chunk = gw/24 -> rows [chunk*32, +32) as 2 row-tiles of 16.
// B-frags (2 n-frags x 8 k) in registers (64 VGPR); launch_bounds caps 128
// VGPR -> 4 waves/SIMD. m92-verified fragment pattern.
// ---------------------------------------------------------------------------
__global__ __launch_bounds__(256, 4) void qkv_mfma_kernel(
    const unsigned short* __restrict__ Xb, const unsigned short* __restrict__ Wt,
    const float* __restrict__ bq, const float* __restrict__ bk,
    const float* __restrict__ bv,
    float* __restrict__ Qs, unsigned short* __restrict__ Kb,
    unsigned short* __restrict__ Vb) {
  const int lane = threadIdx.x & 63;
  const int gw = blockIdx.x * 4 + (threadIdx.x >> 6);  // [0, 12288)
  const int s = gw % 24;
  const int chunk = gw / 24;      // [0, 512)
  const int mat = s >> 3;         // 0=Q 1=K 2=V
  const int c0 = (s & 7) * 32;
  const unsigned short* __restrict__ W = Wt + (size_t)mat * 65536;

  const int lm = lane & 15;
  const int lk = (lane >> 4) * 8;

  short8 Bf[2][8];
  #pragma unroll
  for (int n = 0; n < 2; ++n) {
    #pragma unroll
    for (int k = 0; k < 8; ++k) {
      Bf[n][k] = *reinterpret_cast<const short8*>(
          &W[(size_t)(c0 + n * 16 + lm) * 256 + k * 32 + lk]);
    }
  }

  const float* __restrict__ bias = (mat == 0) ? bq : (mat == 1) ? bk : bv;
  float bias2[2];
  #pragma unroll
  for (int n = 0; n < 2; ++n) bias2[n] = bias[c0 + n * 16 + lm];

  #pragma unroll
  for (int i = 0; i < 2; ++i) {
    const int r0 = chunk * 32 + i * 16;
    short8 Af[8];
    #pragma unroll
    for (int k = 0; k < 8; ++k) {
      Af[k] = *reinterpret_cast<const short8*>(
          &Xb[(size_t)(r0 + lm) * 256 + k * 32 + lk]);
    }
    f32x4 acc[2] = {f32x4{0,0,0,0}, f32x4{0,0,0,0}};
    #pragma unroll
    for (int n = 0; n < 2; ++n) {
      #pragma unroll
      for (int k = 0; k < 8; ++k) {
        acc[n] = __builtin_amdgcn_mfma_f32_16x16x32_bf16(Af[k], Bf[n][k], acc[n], 0, 0, 0);
      }
    }
    #pragma unroll
    for (int n = 0; n < 2; ++n) {
      const int col = c0 + n * 16 + lm;
      #pragma unroll
      for (int r = 0; r < 4; ++r) {
        const int row = r0 + (lane >> 4) * 4 + r;
        const float vres = acc[n][r] + bias2[n];
        if (mat == 0)      Qs[(size_t)row * 256 + col] = vres;
        else if (mat == 1) Kb[(size_t)row * 256 + col] = f2bf(vres);
        else               Vb[(size_t)row * 256 + col] = f2bf(vres);
      }
    }
  }
}

// ---------------------------------------------------------------------------
// Attention: one block per segment (16 consecutive edges), 256 threads.
// Phase 1: tid=(j,h,p): lane dots 16 channels of q (LDS, padded) with K
//   (2x ushort8 vector loads), ONE shfl_xor to combine halves.
// Phase 2: 128 threads=(h,j): softmax over 16 j via 4+4 shfl in 16-lane
//   groups, one exp per thread.
// Phase 3: tid=channel: 16 V-gather FMAs.
// Block->segment swizzle: each XCD (blockIdx%8) works one batch for L2 hits.
// ---------------------------------------------------------------------------
__global__ __launch_bounds__(256) void attn_kernel(
    const float* __restrict__ Q, const unsigned short* __restrict__ K,
    const unsigned short* __restrict__ V, const int* __restrict__ edges,
    float* __restrict__ out) {
  __shared__ int s_n[DEG];        // gathered row ids: b*N + src
  __shared__ float s_q[8 * 36];   // Q row, head h at [h*36, +32) (pad kills conflicts)
  __shared__ float s_sc[DEG][8];  // raw scores [j][h]
  __shared__ float s_w[DEG][8];   // attn weights [j][h]

  // XCD-locality swizzle: bijective since 16384 % 8 == 0. XCD = bx&7 works
  // batch (bx&7)>>1 only -> 8 MB K/V working set per XCD's 4 MB L2.
  const int bx = blockIdx.x;
  const int xcd = bx & 7;
  const int g = (xcd >> 1) * NNODES + (((bx >> 3) << 1) | (xcd & 1));
  const int e0 = g * DEG;
  const int tid = threadIdx.x;

  // header: batch/target are uniform scalar loads; src ids via LDS
  const int b = edges[e0];
  const int qrow = b * NNODES + edges[NEDGES + e0];
  if (tid < DEG) {
    s_n[tid] = b * NNODES + edges[2 * NEDGES + e0 + tid];
  }
  // stage Q row (fp32) into padded LDS
  s_q[(tid >> 5) * 36 + (tid & 31)] = Q[(size_t)qrow * HID + tid];
  __syncthreads();

  // ---- Phase 1: scores ----
  const int j = tid >> 4;
  const int h = (tid >> 1) & 7;
  const int p = tid & 1;
  const int n1 = s_n[j];
  const unsigned short* __restrict__ krow = &K[(size_t)n1 * HID + h * 32 + p * 16];
  const ushort8 k0 = *reinterpret_cast<const ushort8*>(krow);
  const ushort8 k1 = *reinterpret_cast<const ushort8*>(krow + 8);
  const float* __restrict__ qp = &s_q[h * 36 + p * 16];
  float partial = 0.0f;
  #pragma unroll
  for (int i = 0; i < 8; ++i) partial = fmaf(qp[i], bf2f(k0[i]), partial);
  #pragma unroll
  for (int i = 0; i < 8; ++i) partial = fmaf(qp[8 + i], bf2f(k1[i]), partial);
  partial += __shfl_xor(partial, 1);
  if (p == 0) s_sc[j][h] = partial;
  __syncthreads();

  // ---- Phase 2: softmax over j per head ----
  if (tid < 128) {
    const int tj = tid & 15;
    const int th = tid >> 4;
    const float sc = s_sc[tj][th] * 0.17677669529663687f;  // 1/sqrt(DH)
    float mx = sc;
    mx = fmaxf(mx, __shfl_xor(mx, 1));
    mx = fmaxf(mx, __shfl_xor(mx, 2));
    mx = fmaxf(mx, __shfl_xor(mx, 4));
    mx = fmaxf(mx, __shfl_xor(mx, 8));
    const float e = __expf(sc - mx);
    float sum = e;
    sum += __shfl_xor(sum, 1);
    sum += __shfl_xor(sum, 2);
    sum += __shfl_xor(sum, 4);
    sum += __shfl_xor(sum, 8);
    s_w[tj][th] = e / sum;
  }
  __syncthreads();

  // ---- Phase 3: weighted V gather-sum ----
  const int h3 = tid >> 5;
  float acc = 0.0f;
  #pragma unroll
  for (int jj = 0; jj < DEG; ++jj) {
    acc = fmaf(s_w[jj][h3], bf2f(V[(size_t)s_n[jj] * HID + tid]), acc);
  }
  out[(size_t)qrow * HID + tid] = acc;
}

// ---------------------------------------------------------------------------
extern "C" void kernel_launch(void* const* d_in, const int* in_sizes, int n_in,
                              void* d_out, int out_size, void* d_ws, size_t ws_size,
                              hipStream_t stream) {
  const float* X     = (const float*)d_in[0];
  const int*   edges = (const int*)d_in[1];
  const float* Wq    = (const float*)d_in[2];
  const float* bq    = (const float*)d_in[3];
  const float* Wk    = (const float*)d_in[4];
  const float* bk    = (const float*)d_in[5];
  const float* Wv    = (const float*)d_in[6];
  const float* bv    = (const float*)d_in[7];
  float* out = (float*)d_out;

  // Workspace layout: Qs fp32 16MiB | Kb bf16 8MiB | Vb bf16 8MiB |
  //                   Xb bf16 8MiB | Wt bf16 384KiB  (~40.4 MiB total)
  char* w = (char*)d_ws;
  float*          Qs = (float*)w;                 w += (size_t)NROWS * HID * 4;
  unsigned short* Kb = (unsigned short*)w;        w += (size_t)NROWS * HID * 2;
  unsigned short* Vb = (unsigned short*)w;        w += (size_t)NROWS * HID * 2;
  unsigned short* Xb = (unsigned short*)w;        w += (size_t)NROWS * HID * 2;
  unsigned short* Wt = (unsigned short*)w;

  prep_kernel<<<XBLOCKS + WBLOCKS, 256, 0, stream>>>(X, Wq, Wk, Wv, Xb, Wt);
  qkv_mfma_kernel<<<3072, 256, 0, stream>>>(Xb, Wt, bq, bk, bv, Qs, Kb, Vb);
  attn_kernel<<<NROWS, 256, 0, stream>>>(Qs, Kb, Vb, edges, out);
}

// Round 5
// 59.666 us; speedup vs baseline: 3.2443x; 1.4480x over previous
//
#include <hip/hip_runtime.h>
#include <hip/hip_bf16.h>

// Problem constants (fixed by setup_inputs)
#define BATCH 4
#define NNODES 4096
#define HID 256
#define NHEADS 8
#define DH 32
#define DEG 16
#define NEDGES (BATCH * NNODES * DEG)   // 262144
#define NROWS (BATCH * NNODES)          // 16384 node-rows

typedef __attribute__((ext_vector_type(8))) short short8;
typedef __attribute__((ext_vector_type(8))) unsigned short ushort8;
typedef __attribute__((ext_vector_type(4))) unsigned short u16x4;  // NB: 'ushort4' collides with HIP vector types
typedef __attribute__((ext_vector_type(4))) float f32x4;

static __device__ __forceinline__ unsigned short f2bf(float f) {
  __hip_bfloat16 h = __float2bfloat16(f);  // RNE
  return *reinterpret_cast<unsigned short*>(&h);
}
static __device__ __forceinline__ float bf2f(unsigned short u) {
  unsigned int v = ((unsigned int)u) << 16;
  return *reinterpret_cast<float*>(&v);
}

// ---------------------------------------------------------------------------
// Prep: X -> bf16 (blocks [0,2048)).
// Wt permuted layout (96 blocks): element (mat, strip, kk, hi, col, j) =
//   bf16( W_mat[ kk*32 + hi*8 + j ][ strip*64 + col ] )
// i.e. exactly the B-fragment order qkv_mfma's ds_read_b128 wants: each
// 16-lane group (hi) reads a contiguous 256B run -> zero bank conflicts,
// and the global->LDS stage is a plain linear copy.
// ---------------------------------------------------------------------------
#define XBLOCKS 2048
#define WBLOCKS 96
__global__ __launch_bounds__(256) void prep_kernel(
    const float* __restrict__ X,
    const float* __restrict__ Wq, const float* __restrict__ Wk,
    const float* __restrict__ Wv,
    unsigned short* __restrict__ Xb, unsigned short* __restrict__ Wt) {
  const int tid = threadIdx.x;
  if (blockIdx.x < XBLOCKS) {
    const size_t base = (size_t)blockIdx.x * 2048 + (size_t)tid * 8;
    const float4 a = *reinterpret_cast<const float4*>(&X[base]);
    const float4 b = *reinterpret_cast<const float4*>(&X[base + 4]);
    ushort8 o;
    o[0] = f2bf(a.x); o[1] = f2bf(a.y); o[2] = f2bf(a.z); o[3] = f2bf(a.w);
    o[4] = f2bf(b.x); o[5] = f2bf(b.y); o[6] = f2bf(b.z); o[7] = f2bf(b.w);
    *reinterpret_cast<ushort8*>(&Xb[base]) = o;
  } else {
    const int o = (blockIdx.x - XBLOCKS) * 2048 + tid * 8;  // [0, 196608)
    const int mat   = o >> 16;
    const int w     = o & 65535;
    const int strip = w >> 14;
    const int r     = w & 16383;
    const int kk    = r >> 11;
    const int hi    = (r >> 9) & 3;
    const int col   = (r >> 3) & 63;
    const int k0    = kk * 32 + hi * 8;
    const int c     = strip * 64 + col;
    const float* __restrict__ W = (mat == 0) ? Wq : (mat == 1) ? Wk : Wv;
    ushort8 ovec;
    #pragma unroll
    for (int j = 0; j < 8; ++j) {
      ovec[j] = f2bf(W[(size_t)(k0 + j) * HID + c]);
    }
    *reinterpret_cast<ushort8*>(&Wt[o]) = ovec;
  }
}

// ---------------------------------------------------------------------------
// MFMA projection. Grid 3072 blocks (strip-major: s = bx>>8, chunk = bx&255),
// 256 threads = 4 waves. Block computes rows [chunk*64,+64) x cols
// [ (s&3)*64, +64 ) of matrix s>>2. W strip (32KB) staged in LDS once,
// shared by all 4 waves; wave w owns 16 rows.
// MFMA operands SWAPPED: mfma(Bf, Af) -> D[n][m]: lane&15 = X-row,
// (lane>>4)*4+reg = 4 consecutive W-cols -> float4 / packed-bf16x4 stores.
// ---------------------------------------------------------------------------
__global__ __launch_bounds__(256, 4) void qkv_mfma_kernel(
    const unsigned short* __restrict__ Xb, const unsigned short* __restrict__ Wt,
    const float* __restrict__ bq, const float* __restrict__ bk,
    const float* __restrict__ bv,
    float* __restrict__ Qs, unsigned short* __restrict__ Kb,
    unsigned short* __restrict__ Vb) {
  __shared__ unsigned short sW[16384];  // 32 KB: [kk 8][hi 4][col 64][8]

  const int tid = threadIdx.x;
  const int s = blockIdx.x >> 8;        // 0..11  (strip-major for W L2 reuse)
  const int chunk = blockIdx.x & 255;   // 0..255 (64 rows each)
  const int mat = s >> 2;               // 0=Q 1=K 2=V
  const int c0 = (s & 3) * 64;

  // Stage W strip: linear coalesced copy (already in fragment order).
  const unsigned short* __restrict__ Wsrc = Wt + (size_t)(mat * 4 + (s & 3)) * 16384;
  #pragma unroll
  for (int i = 0; i < 8; ++i) {
    const int e = i * 2048 + tid * 8;
    *reinterpret_cast<ushort8*>(&sW[e]) =
        *reinterpret_cast<const ushort8*>(&Wsrc[e]);
  }

  const int lane = tid & 63;
  const int wv = tid >> 6;
  const int lm = lane & 15;
  const int hi = lane >> 4;             // 0..3
  const int lk = hi * 8;
  const int r0 = chunk * 64 + wv * 16;
  const int row = r0 + lm;

  // A-fragments: X rows (bf16), one 16-row tile per wave. Coalesced: the
  // wave's 64 lanes cover 16 rows x 64B contiguous per kk.
  short8 Af[8];
  #pragma unroll
  for (int kk = 0; kk < 8; ++kk) {
    Af[kk] = *reinterpret_cast<const short8*>(
        &Xb[(size_t)row * 256 + kk * 32 + lk]);
  }

  const float* __restrict__ bias = (mat == 0) ? bq : (mat == 1) ? bk : bv;

  __syncthreads();

  #pragma unroll
  for (int nt = 0; nt < 4; ++nt) {
    short8 Bf[8];
    #pragma unroll
    for (int kk = 0; kk < 8; ++kk) {
      Bf[kk] = *reinterpret_cast<const short8*>(
          &sW[kk * 2048 + hi * 512 + (nt * 16 + lm) * 8]);
    }
    f32x4 acc = {0.f, 0.f, 0.f, 0.f};
    #pragma unroll
    for (int kk = 0; kk < 8; ++kk) {
      acc = __builtin_amdgcn_mfma_f32_16x16x32_bf16(Bf[kk], Af[kk], acc, 0, 0, 0);
    }
    const int col0 = c0 + nt * 16 + hi * 4;
    const float4 b4 = *reinterpret_cast<const float4*>(&bias[col0]);
    if (mat == 0) {
      float4 o;
      o.x = acc[0] + b4.x; o.y = acc[1] + b4.y;
      o.z = acc[2] + b4.z; o.w = acc[3] + b4.w;
      *reinterpret_cast<float4*>(&Qs[(size_t)row * 256 + col0]) = o;
    } else {
      u16x4 o;
      o[0] = f2bf(acc[0] + b4.x); o[1] = f2bf(acc[1] + b4.y);
      o[2] = f2bf(acc[2] + b4.z); o[3] = f2bf(acc[3] + b4.w);
      unsigned short* __restrict__ dst = (mat == 1) ? Kb : Vb;
      *reinterpret_cast<u16x4*>(&dst[(size_t)row * 256 + col0]) = o;
    }
  }
}

// ---------------------------------------------------------------------------
// Attention: one block per segment (16 consecutive edges), 256 threads.
// Phase 1: tid=(j,h,p): dot 16 channels vs K (2x ushort8 loads), one shfl.
// Phase 2: 128 threads=(h,j): softmax over 16 j via shfl in 16-lane groups.
// Phase 3: tid=channel: 16 V-gather FMAs.
// XCD swizzle: each XCD works one batch -> K/V L2 locality.
// ---------------------------------------------------------------------------
__global__ __launch_bounds__(256) void attn_kernel(
    const float* __restrict__ Q, const unsigned short* __restrict__ K,
    const unsigned short* __restrict__ V, const int* __restrict__ edges,
    float* __restrict__ out) {
  __shared__ int s_n[DEG];
  __shared__ float s_q[8 * 36];
  __shared__ float s_sc[DEG][8];
  __shared__ float s_w[DEG][8];

  const int bx = blockIdx.x;
  const int xcd = bx & 7;
  const int g = (xcd >> 1) * NNODES + (((bx >> 3) << 1) | (xcd & 1));
  const int e0 = g * DEG;
  const int tid = threadIdx.x;

  const int b = edges[e0];
  const int qrow = b * NNODES + edges[NEDGES + e0];
  if (tid < DEG) {
    s_n[tid] = b * NNODES + edges[2 * NEDGES + e0 + tid];
  }
  s_q[(tid >> 5) * 36 + (tid & 31)] = Q[(size_t)qrow * HID + tid];
  __syncthreads();

  // ---- Phase 1: scores ----
  const int j = tid >> 4;
  const int h = (tid >> 1) & 7;
  const int p = tid & 1;
  const int n1 = s_n[j];
  const unsigned short* __restrict__ krow = &K[(size_t)n1 * HID + h * 32 + p * 16];
  const ushort8 k0 = *reinterpret_cast<const ushort8*>(krow);
  const ushort8 k1 = *reinterpret_cast<const ushort8*>(krow + 8);
  const float* __restrict__ qp = &s_q[h * 36 + p * 16];
  float partial = 0.0f;
  #pragma unroll
  for (int i = 0; i < 8; ++i) partial = fmaf(qp[i], bf2f(k0[i]), partial);
  #pragma unroll
  for (int i = 0; i < 8; ++i) partial = fmaf(qp[8 + i], bf2f(k1[i]), partial);
  partial += __shfl_xor(partial, 1);
  if (p == 0) s_sc[j][h] = partial;
  __syncthreads();

  // ---- Phase 2: softmax over j per head ----
  if (tid < 128) {
    const int tj = tid & 15;
    const int th = tid >> 4;
    const float sc = s_sc[tj][th] * 0.17677669529663687f;  // 1/sqrt(DH)
    float mx = sc;
    mx = fmaxf(mx, __shfl_xor(mx, 1));
    mx = fmaxf(mx, __shfl_xor(mx, 2));
    mx = fmaxf(mx, __shfl_xor(mx, 4));
    mx = fmaxf(mx, __shfl_xor(mx, 8));
    const float e = __expf(sc - mx);
    float sum = e;
    sum += __shfl_xor(sum, 1);
    sum += __shfl_xor(sum, 2);
    sum += __shfl_xor(sum, 4);
    sum += __shfl_xor(sum, 8);
    s_w[tj][th] = e / sum;
  }
  __syncthreads();

  // ---- Phase 3: weighted V gather-sum ----
  const int h3 = tid >> 5;
  float acc = 0.0f;
  #pragma unroll
  for (int jj = 0; jj < DEG; ++jj) {
    acc = fmaf(s_w[jj][h3], bf2f(V[(size_t)s_n[jj] * HID + tid]), acc);
  }
  out[(size_t)qrow * HID + tid] = acc;
}

// ---------------------------------------------------------------------------
extern "C" void kernel_launch(void* const* d_in, const int* in_sizes, int n_in,
                              void* d_out, int out_size, void* d_ws, size_t ws_size,
                              hipStream_t stream) {
  const float* X     = (const float*)d_in[0];
  const int*   edges = (const int*)d_in[1];
  const float* Wq    = (const float*)d_in[2];
  const float* bq    = (const float*)d_in[3];
  const float* Wk    = (const float*)d_in[4];
  const float* bk    = (const float*)d_in[5];
  const float* Wv    = (const float*)d_in[6];
  const float* bv    = (const float*)d_in[7];
  float* out = (float*)d_out;

  // Workspace: Qs fp32 16MiB | Kb bf16 8MiB | Vb bf16 8MiB | Xb bf16 8MiB |
  //            Wt bf16 384KiB  (~40.4 MiB total)
  char* w = (char*)d_ws;
  float*          Qs = (float*)w;                 w += (size_t)NROWS * HID * 4;
  unsigned short* Kb = (unsigned short*)w;        w += (size_t)NROWS * HID * 2;
  unsigned short* Vb = (unsigned short*)w;        w += (size_t)NROWS * HID * 2;
  unsigned short* Xb = (unsigned short*)w;        w += (size_t)NROWS * HID * 2;
  unsigned short* Wt = (unsigned short*)w;

  prep_kernel<<<XBLOCKS + WBLOCKS, 256, 0, stream>>>(X, Wq, Wk, Wv, Xb, Wt);
  qkv_mfma_kernel<<<3072, 256, 0, stream>>>(Xb, Wt, bq, bk, bv, Qs, Kb, Vb);
  attn_kernel<<<NROWS, 256, 0, stream>>>(Qs, Kb, Vb, edges, out);
}